// Round 8
// baseline (108.874 us; speedup 1.0000x reference)
//
#include <hip/hip_runtime.h>
#include <hip/hip_bf16.h>

// LowRankBilinearPooling: out[b,o] = (sum_i relu(x1 W1))_h * (sum_j relu(x2 W2))_h @ Wp + bp*196^2
// B=16, N=196, C=768, H=512, O=128. fp32 in/out; bf16 MFMA inside.
// 3 dispatches: w_tile (W -> fragment-ordered bf16, + zero-row) ->
//   gemm+relu+rowsum (fragment-direct, NO LDS/barriers in K-loop) -> proj.
// K must NOT be split across blocks (relu sits between K-sum and row-sum).

#define NB 16
#define NROW 196
#define KC_ 768
#define HH 512
#define OO 128

using short8 = __attribute__((ext_vector_type(8))) short;
using f32x16 = __attribute__((ext_vector_type(16))) float;

__device__ __forceinline__ short2 pk2bf(float a, float b) {
    // v_cvt_pk_bf16_f32 on gfx950
    __hip_bfloat162 h = __float22bfloat162_rn(make_float2(a, b));
    union { __hip_bfloat162 h; short2 s; } u; u.h = h;
    return u.s;
}

// Prepass: W1/W2 -> bf16 in MFMA *fragment* order.
// Plane bb=(branch*4+ht)*12+kc (16 KB). Unit (kp,sp,a,m), j=0..7:
//   value = W[(kc*64+kp*8+j)*512 + ht*128 + sp*64 + a*32 + m]
// In the gemm, lane l=q*32+m of wave-strip sp reads, for ks: kp=ks*2+q,
// acc a: one short8 at ((kp*2+sp)*2+a)*256 + m*8 — contiguous & coalesced.
// Block 0 additionally zeroes the 768-float scratch row (for padded A rows).
__global__ __launch_bounds__(256)
void w_tile(const float* __restrict__ W1, const float* __restrict__ W2,
            unsigned short* __restrict__ Wt, float* __restrict__ zrow) {
    const int t = threadIdx.x;
    const int bb = blockIdx.x;              // branch*48 + ht*12 + kc
    if (bb == 0) {
        zrow[t] = 0.f; zrow[t + 256] = 0.f; zrow[t + 512] = 0.f;
    }
    const int branch = bb / 48;
    const int rem = bb % 48;
    const int ht = rem / 12;
    const int kc = rem % 12;
    const float* __restrict__ W = branch ? W2 : W1;
    unsigned short* __restrict__ out = Wt + (size_t)bb * 8192;
#pragma unroll
    for (int i = 0; i < 4; ++i) {
        const int u = i * 256 + t;          // 0..1023
        const int m  = u & 31;
        const int a  = (u >> 5) & 1;
        const int sp = (u >> 6) & 1;
        const int kp = u >> 7;              // 0..7
        const float* src = W + (kc * 64 + kp * 8) * HH + ht * 128 + sp * 64 + a * 32 + m;
        float f[8];
#pragma unroll
        for (int j = 0; j < 8; ++j) f[j] = src[j * HH];   // lanes walk m,a,sp: coalesced
        short8 v; short2 s;
#pragma unroll
        for (int j = 0; j < 4; ++j) {
            s = pk2bf(f[2 * j], f[2 * j + 1]); v[2 * j] = s.x; v[2 * j + 1] = s.y;
        }
        *(short8*)(out + u * 8) = v;
    }
}

// Kernel 1: fused GEMM + relu + row-sum, fragment-direct (no K-loop LDS/barriers).
// Grid: 512 blocks = 2(branch) x 16(b) [low 5 bits: XCD-shared] x 4(ht) x 4(mq).
// Block: 256 thr = 4 waves = (mp 0..1: 32-row tile) x (sp 0..1: 64-col strip),
// 2 accumulators/wave. Tile 64x128, FULL K=768. Ping-pong register prefetch.
__global__ __launch_bounds__(256, 2)
void gemm_relu_rowsum(const float* __restrict__ x1, const float* __restrict__ x2,
                      const unsigned short* __restrict__ Wt,
                      const float* __restrict__ zrow,
                      float* __restrict__ sbuf) {
    __shared__ float psum[8 * 32];

    const int bid = blockIdx.x;
    const int p  = bid & 31;           // (branch,b): all 16 tiles of x[b] share an XCD
    const int tt = bid >> 5;           // 0..15
    const int branch = p >> 4;
    const int b      = p & 15;
    const int ht = tt >> 2;            // 0..3: 128-col tile
    const int mq = tt & 3;             // 0..3: 64-row quarter

    const float* __restrict__ x = branch ? x2 : x1;
    const unsigned short* __restrict__ Wtb = Wt + (size_t)((branch * 4 + ht) * 12) * 8192;

    const int t  = threadIdx.x;
    const int w  = t >> 6;             // wave 0..3
    const int l  = t & 63;
    const int m  = l & 31;
    const int q  = l >> 5;
    const int sp = w & 1;              // 64-col strip
    const int mp = w >> 1;             // 32-row tile

    // Lane's fixed A row; padded rows read the zeroed scratch row.
    const int r_abs = mq * 64 + mp * 32 + m;
    const float* xrow = (r_abs < NROW) ? (x + (size_t)(b * NROW + r_abs) * KC_) : zrow;

    // Fragment loads for one 64-k chunk: fa[2*ks],fa[2*ks+1] = 8 fp32 of A;
    // fb[2*ks+a] = short8 B operand for acc a. All addresses per-lane static.
    auto load_frag = [&](float4 (&fa)[8], short8 (&fb)[8], int kc) {
        const float* xp = xrow + kc * 64;
        const unsigned short* wp = Wtb + kc * 8192;
#pragma unroll
        for (int ks = 0; ks < 4; ++ks) {
            const int kp = ks * 2 + q;
            fa[2 * ks]     = *(const float4*)(xp + kp * 8);
            fa[2 * ks + 1] = *(const float4*)(xp + kp * 8 + 4);
            const unsigned short* bp_ = wp + ((kp * 2 + sp) * 2) * 256 + m * 8;
            fb[2 * ks]     = *(const short8*)(bp_);        // a=0
            fb[2 * ks + 1] = *(const short8*)(bp_ + 256);  // a=1
        }
    };

    f32x16 acc0 = {}, acc1 = {};

    auto compute = [&](const float4 (&fa)[8], const short8 (&fb)[8]) {
#pragma unroll
        for (int ks = 0; ks < 4; ++ks) {
            const float4 lo = fa[2 * ks], hi = fa[2 * ks + 1];
            short8 af; short2 s;
            s = pk2bf(lo.x, lo.y); af[0] = s.x; af[1] = s.y;
            s = pk2bf(lo.z, lo.w); af[2] = s.x; af[3] = s.y;
            s = pk2bf(hi.x, hi.y); af[4] = s.x; af[5] = s.y;
            s = pk2bf(hi.z, hi.w); af[6] = s.x; af[7] = s.y;
            acc0 = __builtin_amdgcn_mfma_f32_32x32x16_bf16(af, fb[2 * ks],     acc0, 0, 0, 0);
            acc1 = __builtin_amdgcn_mfma_f32_32x32x16_bf16(af, fb[2 * ks + 1], acc1, 0, 0, 0);
        }
    };

    float4 a0[8], a1[8]; short8 b0f[8], b1f[8];
    load_frag(a0, b0f, 0);
#pragma unroll 1
    for (int j = 0; j < 6; ++j) {
        load_frag(a1, b1f, 2 * j + 1);      // prefetch odd chunk
        compute(a0, b0f);
        if (j < 5) load_frag(a0, b0f, 2 * j + 2);  // prefetch next even chunk
        compute(a1, b1f);
    }

    // relu + sum over rows (after full-K accumulation — the only legal place).
    // C layout: col = lane&31 (m101); lanes l and l^32 together cover all 32 rows.
    float cs0 = 0.f, cs1 = 0.f;
#pragma unroll
    for (int r = 0; r < 16; ++r) {
        cs0 += fmaxf(acc0[r], 0.f);
        cs1 += fmaxf(acc1[r], 0.f);
    }
    cs0 += __shfl_xor(cs0, 32);
    cs1 += __shfl_xor(cs1, 32);
    if (l < 32) {
        psum[((sp * 2 + 0) * 2 + mp) * 32 + l] = cs0;  // strip sp*2:   cols sp*64+0..31
        psum[((sp * 2 + 1) * 2 + mp) * 32 + l] = cs1;  // strip sp*2+1: cols sp*64+32..63
    }
    __syncthreads();
    if (t < 128) {
        const int ct = t >> 5;             // strip 0..3
        const int cl = t & 31;
        const float v = psum[(ct * 2 + 0) * 32 + cl] + psum[(ct * 2 + 1) * 32 + cl];
        // plane = branch*4 + mq : branch-0 planes 0..3, branch-1 planes 4..7
        sbuf[((branch * 4 + mq) * NB + b) * HH + ht * 128 + t] = v;
    }
}

// Kernel 2: out[b,o] = sum_h (s1[b,h]*s2[b,h]) * Wp[h,o] + bp[o]*196^2
// s1 = planes 0..3 summed, s2 = planes 4..7 summed (mq partials, each relu'd full-K).
__global__ __launch_bounds__(512)
void proj_kernel(const float* __restrict__ sbuf, const float* __restrict__ Wp,
                 const float* __restrict__ bp, float* __restrict__ out) {
    __shared__ float spl[HH];
    __shared__ float red[4][OO];
    const int b = blockIdx.x, t = threadIdx.x;
    {
        float s1 = 0.f, s2 = 0.f;
#pragma unroll
        for (int i = 0; i < 4; ++i) {
            s1 += sbuf[((0 + i) * NB + b) * HH + t];
            s2 += sbuf[((4 + i) * NB + b) * HH + t];
        }
        spl[t] = s1 * s2;
    }
    __syncthreads();
    const int to = t & 127, hq = t >> 7;
    float acc = 0.f;
#pragma unroll 8
    for (int h = hq * 128; h < hq * 128 + 128; ++h)
        acc += spl[h] * Wp[h * OO + to];
    red[hq][to] = acc;
    __syncthreads();
    if (t < OO)
        out[b * OO + t] = red[0][t] + red[1][t] + red[2][t] + red[3][t]
                        + bp[t] * 38416.0f;   // 196*196
}

extern "C" void kernel_launch(void* const* d_in, const int* in_sizes, int n_in,
                              void* d_out, int out_size, void* d_ws, size_t ws_size,
                              hipStream_t stream) {
    const float* x1 = (const float*)d_in[0];
    const float* x2 = (const float*)d_in[1];
    const float* W1 = (const float*)d_in[2];
    const float* W2 = (const float*)d_in[3];
    const float* Wp = (const float*)d_in[4];
    const float* bp = (const float*)d_in[5];
    float* sbuf = (float*)d_ws;                                    // 8*16*512 floats = 256 KB
    unsigned short* Wt = (unsigned short*)((char*)d_ws + 262144);  // 1.5 MB, fragment order
    float* zrow = (float*)((char*)d_ws + 262144 + 1572864);        // 768 zeros

    w_tile<<<96, 256, 0, stream>>>(W1, W2, Wt, zrow);
    gemm_relu_rowsum<<<512, 256, 0, stream>>>(x1, x2, Wt, zrow, sbuf);
    proj_kernel<<<NB, 512, 0, stream>>>(sbuf, Wp, bp, (float*)d_out);
}